// Round 8
// baseline (524.983 us; speedup 1.0000x reference)
//
#include <hip/hip_runtime.h>
#include <math.h>

#define NN 100000
#define EE 3200000
#define FF 128
#define HH 16
#define CC 10
#define PC 12           // padded conv2 feature stride (float4-friendly)
#define KK1 25000
#define KK2 6250

// bucket-sort CSR build parameters
#define NBIN 512        // coarse buckets; used = ceil(NN/256) = 391
#define BUCK_SHIFT 8    // bucket = dst >> 8  (256 nodes per bucket)
#define BUCK_MASK 255
#define ABLK 256        // blocks in passes A and C
#define EPB (EE / ABLK) // 12500 edges per block (exact)
#define NBUCK ((NN + 255) / 256)  // 391

#define DEG2_BLKS ((KK1 + 15) / 16)        // 1563
#define XW2_BLKS ((KK1 * PC + 255) / 256)  // 1172

// fused top-k control block (zeroed once by the control-region memset)
struct TopkCtl {
  unsigned prefix;   // accumulated winning high bits; after pass2 = full key T
  unsigned kcur;     // remaining needed among candidates matching prefix
  unsigned ctr_gt;
  unsigned ctr_eq;
  unsigned done0, done1, done2, pad;
};

__device__ __forceinline__ unsigned fkey(float f) {
  unsigned u = __float_as_uint(f);
  return (u & 0x80000000u) ? ~u : (u | 0x80000000u);
}

// ---------------- conv1 GEMM: h0 = x @ W1  ([N,128] @ [128,16]) ----------------
__global__ __launch_bounds__(256) void k_xw1(const float* __restrict__ x,
                                             const float* __restrict__ W1,
                                             float* __restrict__ h0) {
  __shared__ float sW[FF * HH];     // 8 KB
  __shared__ float sx[16][FF];      // 8 KB
  int t = threadIdx.x;
  for (int i = t; i < FF * HH; i += 256) sW[i] = W1[i];
  int base = blockIdx.x * 16;
  for (int i = t; i < 16 * FF; i += 256) {
    int r = i >> 7, c = i & 127;
    int node = base + r;
    sx[r][c] = (node < NN) ? x[(size_t)node * FF + c] : 0.f;
  }
  __syncthreads();
  int r = t >> 4;   // node in tile
  int o = t & 15;   // output col
  float acc = 0.f;
#pragma unroll
  for (int k = 0; k < FF; ++k) acc += sx[r][k] * sW[k * HH + o];
  int node = base + r;
  if (node < NN) h0[node * HH + o] = acc;
}

// ---------------- CSR build: atomic-free two-level bucket sort ----------------
__global__ __launch_bounds__(256) void k_bhist(const int* __restrict__ dst,
                                               unsigned* __restrict__ Hist) {
  __shared__ unsigned sh[NBIN];
  int t = threadIdx.x;
  for (int i = t; i < NBIN; i += 256) sh[i] = 0;
  __syncthreads();
  int base = blockIdx.x * EPB;
  for (int i = base + t; i < base + EPB; i += 256)
    atomicAdd(&sh[dst[i] >> BUCK_SHIFT], 1u);
  __syncthreads();
  for (int i = t; i < NBIN; i += 256) Hist[blockIdx.x * NBIN + i] = sh[i];
}

__global__ __launch_bounds__(64) void k_bcursor(unsigned* __restrict__ Hist,
                                                unsigned* __restrict__ Tot) {
  int bin = blockIdx.x * 64 + threadIdx.x;
  unsigned run = 0;
#pragma unroll 8
  for (int b = 0; b < ABLK; ++b) {
    unsigned c = Hist[b * NBIN + bin];
    Hist[b * NBIN + bin] = run;          // becomes per-block exclusive prefix
    run += c;
  }
  Tot[bin] = run;
}

__global__ __launch_bounds__(512) void k_bscan(const unsigned* __restrict__ Tot,
                                               unsigned* __restrict__ BucketOff) {
  __shared__ unsigned s[NBIN];
  int t = threadIdx.x;
  unsigned v = Tot[t];
  s[t] = v;
  __syncthreads();
  for (int off = 1; off < NBIN; off <<= 1) {
    unsigned u = (t >= off) ? s[t - off] : 0;
    __syncthreads();
    s[t] += u;
    __syncthreads();
  }
  BucketOff[t] = s[t] - v;
  if (t == NBIN - 1) BucketOff[NBIN] = s[t];   // == EE
}

// packed = (dst&255)<<17 | src   (src < 2^17)
__global__ __launch_bounds__(256) void k_bscatter(const int* __restrict__ src,
                                                  const int* __restrict__ dst,
                                                  const unsigned* __restrict__ Hist,
                                                  const unsigned* __restrict__ BucketOff,
                                                  unsigned* __restrict__ packed) {
  __shared__ unsigned cur[NBIN];
  int t = threadIdx.x;
  for (int i = t; i < NBIN; i += 256)
    cur[i] = BucketOff[i] + Hist[blockIdx.x * NBIN + i];
  __syncthreads();
  int base = blockIdx.x * EPB;
  for (int i = base + t; i < base + EPB; i += 256) {
    int d = dst[i];
    unsigned pos = atomicAdd(&cur[d >> BUCK_SHIFT], 1u);
    packed[pos] = ((unsigned)(d & BUCK_MASK) << 17) | (unsigned)src[i];
  }
}

__global__ __launch_bounds__(256) void k_bfine(const unsigned* __restrict__ packed,
                                               const unsigned* __restrict__ BucketOff,
                                               int* __restrict__ rowstart,
                                               float* __restrict__ dinv,
                                               int* __restrict__ csr) {
  __shared__ unsigned fcnt[256], fpos[256], fcur[256];
  int bin = blockIdx.x;
  int t = threadIdx.x;
  unsigned b0 = BucketOff[bin], b1 = BucketOff[bin + 1];
  fcnt[t] = 0;
  __syncthreads();
  for (unsigned e = b0 + t; e < b1; e += 256)
    atomicAdd(&fcnt[packed[e] >> 17], 1u);
  __syncthreads();
  unsigned v = fcnt[t];
  fpos[t] = v;
  __syncthreads();
  for (int off = 1; off < 256; off <<= 1) {
    unsigned u = (t >= off) ? fpos[t - off] : 0;
    __syncthreads();
    fpos[t] += u;
    __syncthreads();
  }
  unsigned excl = fpos[t] - v;
  fcur[t] = b0 + excl;
  int node = bin * 256 + t;
  if (node < NN) {
    rowstart[node] = (int)(b0 + excl);
    dinv[node] = rsqrtf((float)v + 1.0f);    // deg = cnt + 1 (self-loop)
  }
  if (bin == 0 && t == 0) rowstart[NN] = EE;
  __syncthreads();
  for (unsigned e = b0 + t; e < b1; e += 256) {
    unsigned p = packed[e];
    unsigned pos = atomicAdd(&fcur[p >> 17], 1u);
    csr[pos] = (int)(p & 0x1FFFFu);
  }
}

// ---------------- conv1: wave-per-node, 32 edges in flight (unroll x2) ----------
__global__ __launch_bounds__(256) void k_conv1(const float* __restrict__ h0,
                                               const float* __restrict__ dinv,
                                               const int* __restrict__ rowstart,
                                               const int* __restrict__ csr,
                                               const float* __restrict__ b1,
                                               const float* __restrict__ wroot,
                                               const float* __restrict__ wrel,
                                               const float* __restrict__ bp,
                                               float* __restrict__ h,
                                               float* __restrict__ score,
                                               float* __restrict__ hrel) {
  int node = blockIdx.x * 4 + (threadIdx.x >> 6);
  if (node >= NN) return;
  int lane = threadIdx.x & 63;
  int eslot = lane >> 2;          // 0..15
  int kq = lane & 3;              // float4 quarter
  int s0 = rowstart[node], s1 = rowstart[node + 1];
  float ax = 0.f, ay = 0.f, az = 0.f, aw = 0.f;
  float bx_ = 0.f, by_ = 0.f, bz_ = 0.f, bw_ = 0.f;
  for (int base = s0; base < s1; base += 32) {
    int i1 = base + eslot;
    int i2 = base + 16 + eslot;
    bool on1 = i1 < s1, on2 = i2 < s1;
    int sv1 = on1 ? csr[i1] : 0;
    int sv2 = on2 ? csr[i2] : 0;
    float dv1 = on1 ? dinv[sv1] : 0.f;
    float dv2 = on2 ? dinv[sv2] : 0.f;
    float4 h1 = *(const float4*)(h0 + sv1 * HH + kq * 4);
    float4 h2v = *(const float4*)(h0 + sv2 * HH + kq * 4);
    ax += h1.x * dv1; ay += h1.y * dv1; az += h1.z * dv1; aw += h1.w * dv1;
    bx_ += h2v.x * dv2; by_ += h2v.y * dv2; bz_ += h2v.z * dv2; bw_ += h2v.w * dv2;
  }
  ax += bx_; ay += by_; az += bz_; aw += bw_;
#pragma unroll
  for (int m = 4; m <= 32; m <<= 1) {
    ax += __shfl_xor(ax, m);
    ay += __shfl_xor(ay, m);
    az += __shfl_xor(az, m);
    aw += __shfl_xor(aw, m);
  }
  float di = dinv[node];
  float4 hs = *(const float4*)(h0 + node * HH + kq * 4);
  float vx = ax * di + hs.x * di * di + b1[kq * 4 + 0];
  float vy = ay * di + hs.y * di * di + b1[kq * 4 + 1];
  float vz = az * di + hs.z * di * di + b1[kq * 4 + 2];
  float vw = aw * di + hs.w * di * di + b1[kq * 4 + 3];
  vx = vx > 0.f ? vx : 0.f;
  vy = vy > 0.f ? vy : 0.f;
  vz = vz > 0.f ? vz : 0.f;
  vw = vw > 0.f ? vw : 0.f;
  if (eslot == 0) {
    float4 o4 = make_float4(vx, vy, vz, vw);
    *(float4*)(h + node * HH + kq * 4) = o4;
  }
  float sr = vx * wroot[kq * 4] + vy * wroot[kq * 4 + 1] +
             vz * wroot[kq * 4 + 2] + vw * wroot[kq * 4 + 3];
  float sl = vx * wrel[kq * 4] + vy * wrel[kq * 4 + 1] +
             vz * wrel[kq * 4 + 2] + vw * wrel[kq * 4 + 3];
  sr += __shfl_xor(sr, 1);
  sr += __shfl_xor(sr, 2);
  sl += __shfl_xor(sl, 1);
  sl += __shfl_xor(sl, 2);
  if (lane == 0) {
    score[node] = sr + bp[0];
    hrel[node] = sl;
  }
}

// score[d] += sum over in-edges of hrel[src]; 16 lanes per node, no atomics
__global__ __launch_bounds__(256) void k_scoreg(const int* __restrict__ rowstart,
                                                const int* __restrict__ csr,
                                                const float* __restrict__ hrel,
                                                float* __restrict__ score) {
  int node = blockIdx.x * 16 + (threadIdx.x >> 4);
  if (node >= NN) return;
  int lane = threadIdx.x & 15;
  int s0 = rowstart[node], s1 = rowstart[node + 1];
  float sum = 0.f;
  for (int e = s0 + lane; e < s1; e += 16) sum += hrel[csr[e]];
#pragma unroll
  for (int m = 8; m; m >>= 1) sum += __shfl_xor(sum, m, 16);
  if (lane == 0) score[node] += sum;
}

// ---------------- fused top-k radix pass (hist + last-block scan) ----------------
// PASS 0: bin = key>>21 (11b). PASS 1: filter key>>21==prefix, bin=(key>>10)&2047.
// PASS 2: filter key>>10==prefix, bin=key&1023. After PASS 2 prefix == full key T.
template <int PASS>
__global__ __launch_bounds__(256) void k_topk_pass(const float* __restrict__ vals,
                                                   int n, int K, TopkCtl* ctl,
                                                   unsigned* __restrict__ ghist,
                                                   int nblocks) {
  const int NB = (PASS == 2) ? 1024 : 2048;
  __shared__ unsigned sh[2048];
  int t = threadIdx.x;
  for (int i = t; i < NB; i += 256) sh[i] = 0;
  unsigned prefix = 0, kcur = (unsigned)K;
  if (PASS > 0) {
    prefix = __hip_atomic_load(&ctl->prefix, __ATOMIC_RELAXED, __HIP_MEMORY_SCOPE_AGENT);
    kcur = __hip_atomic_load(&ctl->kcur, __ATOMIC_RELAXED, __HIP_MEMORY_SCOPE_AGENT);
  }
  __syncthreads();
  for (int i = blockIdx.x * 256 + t; i < n; i += nblocks * 256) {
    unsigned key = fkey(vals[i]);
    bool ok;
    unsigned bin;
    if (PASS == 0) { ok = true; bin = key >> 21; }
    else if (PASS == 1) { ok = (key >> 21) == prefix; bin = (key >> 10) & 2047u; }
    else { ok = (key >> 10) == prefix; bin = key & 1023u; }
    if (ok) atomicAdd(&sh[bin], 1u);
  }
  __syncthreads();
  for (int i = t; i < NB; i += 256) if (sh[i]) atomicAdd(&ghist[i], sh[i]);
  __threadfence();
  __shared__ unsigned lastflag;
  if (t == 0) {
    unsigned* done = (PASS == 0) ? &ctl->done0 : (PASS == 1) ? &ctl->done1 : &ctl->done2;
    unsigned old = atomicAdd(done, 1u);
    lastflag = (old == (unsigned)(nblocks - 1)) ? 1u : 0u;
  }
  __syncthreads();
  if (!lastflag) return;
  __threadfence();
  // last block: suffix-scan over NB bins, pick winner bin
  const int PER = NB / 256;            // 8 or 4
  unsigned loc[8];
  unsigned psum = 0;
#pragma unroll
  for (int j = 0; j < PER; ++j) {
    loc[j] = __hip_atomic_load(&ghist[t * PER + j], __ATOMIC_RELAXED,
                               __HIP_MEMORY_SCOPE_AGENT);
    psum += loc[j];
  }
  __shared__ unsigned ss[256];
  ss[t] = psum;
  __syncthreads();
  for (int off = 1; off < 256; off <<= 1) {
    unsigned u = (t + off < 256) ? ss[t + off] : 0;
    __syncthreads();
    ss[t] += u;
    __syncthreads();
  }
  unsigned above = (t < 255) ? ss[t + 1] : 0;   // count in bins >= (t+1)*PER
  unsigned run = above;
  int winner = -1;
  unsigned newk = 0;
  for (int j = PER - 1; j >= 0; --j) {
    unsigned tot = run + loc[j];
    if (tot >= kcur && run < kcur) { winner = t * PER + j; newk = kcur - run; }
    run = tot;
  }
  if (winner >= 0) {
    unsigned npfx = (PASS == 0) ? (unsigned)winner
                  : (PASS == 1) ? ((prefix << 11) | (unsigned)winner)
                                : ((prefix << 10) | (unsigned)winner);
    __hip_atomic_store(&ctl->prefix, npfx, __ATOMIC_RELAXED, __HIP_MEMORY_SCOPE_AGENT);
    __hip_atomic_store(&ctl->kcur, newk, __ATOMIC_RELAXED, __HIP_MEMORY_SCOPE_AGENT);
  }
  // zero ghist for the next pass (atomic stores -> visible to next pass's atomics)
  for (int i = t; i < 2048; i += 256)
    __hip_atomic_store(&ghist[i], 0u, __ATOMIC_RELAXED, __HIP_MEMORY_SCOPE_AGENT);
}

// pool1 selection: new_idx + orig_of + gather-scale x1 = h[kept]*tanh(score)
__global__ void k_select1(const float* __restrict__ score, const float* __restrict__ h,
                          TopkCtl* st, int* __restrict__ new_idx,
                          int* __restrict__ orig_of, float* __restrict__ x1) {
  int i = blockIdx.x * blockDim.x + threadIdx.x;
  if (i >= NN) return;
  float sc = score[i];
  unsigned key = fkey(sc);
  unsigned T = st->prefix;
  int id = -1;
  if (key > T) {
    id = (int)atomicAdd(&st->ctr_gt, 1u);
  } else if (key == T) {
    unsigned p = atomicAdd(&st->ctr_eq, 1u);
    unsigned kneed = st->kcur;
    if (p < kneed) id = (KK1 - (int)kneed) + (int)p;
  }
  new_idx[i] = id;
  if (id >= 0) {
    orig_of[id] = i;
    float tv = tanhf(sc);
#pragma unroll
    for (int k = 0; k < HH; ++k) x1[id * HH + k] = h[i * HH + k] * tv;
  }
}

// ---------------- fused deg2 + xw2 (independent work, one dispatch) --------------
__global__ __launch_bounds__(256) void k_deg2xw2(const int* __restrict__ orig_of,
                                                 const int* __restrict__ rowstart,
                                                 const int* __restrict__ csr,
                                                 const int* __restrict__ nidx,
                                                 float* __restrict__ dinv2,
                                                 const float* __restrict__ x1,
                                                 const float* __restrict__ W2,
                                                 float* __restrict__ h20) {
  int b = blockIdx.x;
  if (b < DEG2_BLKS) {
    int j = b * 16 + (threadIdx.x >> 4);
    if (j >= KK1) return;
    int lane = threadIdx.x & 15;
    int o = orig_of[j];
    int s0 = rowstart[o], s1 = rowstart[o + 1];
    int c = 0;
    for (int e = s0 + lane; e < s1; e += 16) c += (nidx[csr[e]] >= 0) ? 1 : 0;
#pragma unroll
    for (int m = 8; m; m >>= 1) c += __shfl_xor(c, m, 16);
    if (lane == 0) dinv2[j] = rsqrtf((float)c + 1.0f);
  } else {
    int t = (b - DEG2_BLKS) * 256 + threadIdx.x;
    if (t >= KK1 * PC) return;
    int node = t / PC;
    int o = t - node * PC;
    float acc = 0.f;
    if (o < CC) {
#pragma unroll
      for (int k = 0; k < HH; ++k) acc += x1[node * HH + k] * W2[k * CC + o];
    }
    h20[t] = acc;
  }
}

// conv2: wave-per-node, edge-parallel float4 (stride-12 rows; kq=3 lanes inert)
__global__ __launch_bounds__(256) void k_conv2(const float* __restrict__ h20,
                                               const float* __restrict__ dinv2,
                                               const int* __restrict__ orig_of,
                                               const int* __restrict__ rowstart,
                                               const int* __restrict__ csr,
                                               const int* __restrict__ nidx,
                                               const float* __restrict__ b2,
                                               const float* __restrict__ wroot,
                                               const float* __restrict__ wrel,
                                               const float* __restrict__ bp,
                                               float* __restrict__ h2,
                                               float* __restrict__ score2,
                                               float* __restrict__ h2rel) {
  int j = blockIdx.x * 4 + (threadIdx.x >> 6);
  if (j >= KK1) return;
  int lane = threadIdx.x & 63;
  int eslot = lane >> 2;
  int kq = lane & 3;
  int o = orig_of[j];
  int s0 = rowstart[o], s1 = rowstart[o + 1];
  float ax = 0.f, ay = 0.f, az = 0.f, aw = 0.f;
  for (int base = s0; base < s1; base += 16) {
    int idx = base + eslot;
    bool on = idx < s1;
    int sv = on ? nidx[csr[idx]] : -1;
    float dv = (sv >= 0) ? dinv2[sv] : 0.f;
    int sva = (sv >= 0) ? sv : 0;
    float4 hv = *(const float4*)(h20 + sva * PC + ((kq < 3) ? kq * 4 : 8));
    if (kq == 3) dv = 0.f;
    ax += hv.x * dv;
    ay += hv.y * dv;
    az += hv.z * dv;
    aw += hv.w * dv;
  }
#pragma unroll
  for (int m = 4; m <= 32; m <<= 1) {
    ax += __shfl_xor(ax, m);
    ay += __shfl_xor(ay, m);
    az += __shfl_xor(az, m);
    aw += __shfl_xor(aw, m);
  }
  float di = dinv2[j];
  int kb = (kq < 3) ? kq * 4 : 8;
  float4 hs = *(const float4*)(h20 + j * PC + kb);
  float bx = (kb + 0 < CC) ? b2[kb + 0] : 0.f;
  float by = (kb + 1 < CC) ? b2[kb + 1] : 0.f;
  float bz = (kb + 2 < CC) ? b2[kb + 2] : 0.f;
  float bw = (kb + 3 < CC) ? b2[kb + 3] : 0.f;
  float vx = ax * di + hs.x * di * di + bx;
  float vy = ay * di + hs.y * di * di + by;
  float vz = az * di + hs.z * di * di + bz;
  float vw = aw * di + hs.w * di * di + bw;
  if (kq == 3) { vx = vy = vz = vw = 0.f; }
  if (kb + 2 >= CC) vz = 0.f;
  if (kb + 3 >= CC) vw = 0.f;
  if (eslot == 0 && kq < 3) {
    float4 o4 = make_float4(vx, vy, vz, vw);
    *(float4*)(h2 + j * PC + kq * 4) = o4;
  }
  float wrx = (kb + 0 < CC) ? wroot[kb + 0] : 0.f;
  float wry = (kb + 1 < CC) ? wroot[kb + 1] : 0.f;
  float wrz = (kb + 2 < CC) ? wroot[kb + 2] : 0.f;
  float wrw = (kb + 3 < CC) ? wroot[kb + 3] : 0.f;
  float wlx = (kb + 0 < CC) ? wrel[kb + 0] : 0.f;
  float wly = (kb + 1 < CC) ? wrel[kb + 1] : 0.f;
  float wlz = (kb + 2 < CC) ? wrel[kb + 2] : 0.f;
  float wlw = (kb + 3 < CC) ? wrel[kb + 3] : 0.f;
  float sr = (kq == 3) ? 0.f : (vx * wrx + vy * wry + vz * wrz + vw * wrw);
  float sl = (kq == 3) ? 0.f : (vx * wlx + vy * wly + vz * wlz + vw * wlw);
  sr += __shfl_xor(sr, 1);
  sr += __shfl_xor(sr, 2);
  sl += __shfl_xor(sl, 1);
  sl += __shfl_xor(sl, 2);
  if (lane == 0) {
    score2[j] = sr + bp[0];
    h2rel[j] = sl;
  }
}

// score2[j] += sum over surviving in-edges of h2rel[src]; 16 lanes per node
__global__ __launch_bounds__(256) void k_score2g(const int* __restrict__ orig_of,
                                                 const int* __restrict__ rowstart,
                                                 const int* __restrict__ csr,
                                                 const int* __restrict__ nidx,
                                                 const float* __restrict__ h2rel,
                                                 float* __restrict__ score2) {
  int j = blockIdx.x * 16 + (threadIdx.x >> 4);
  if (j >= KK1) return;
  int lane = threadIdx.x & 15;
  int o = orig_of[j];
  int s0 = rowstart[o], s1 = rowstart[o + 1];
  float sum = 0.f;
  for (int e = s0 + lane; e < s1; e += 16) {
    int s = nidx[csr[e]];
    if (s >= 0) sum += h2rel[s];
  }
#pragma unroll
  for (int m = 8; m; m >>= 1) sum += __shfl_xor(sum, m, 16);
  if (lane == 0) score2[j] += sum;
}

// pool2 selection folded into output accumulator; wave+LDS reduce, 10 atomics/block
__global__ __launch_bounds__(256) void k_final_accum(const float* __restrict__ score,
                                                     const float* __restrict__ h2,
                                                     TopkCtl* st, float* __restrict__ acc) {
  int i = blockIdx.x * blockDim.x + threadIdx.x;
  float tv = 0.f;
  if (i < KK1) {
    float sc = score[i];
    unsigned key = fkey(sc);
    unsigned T = st->prefix;
    bool keep = false;
    if (key > T) {
      keep = true;
    } else if (key == T) {
      unsigned p = atomicAdd(&st->ctr_eq, 1u);
      keep = (p < st->kcur);
    }
    if (keep) tv = tanhf(sc);
  }
  __shared__ float sacc[CC];
  if (threadIdx.x < CC) sacc[threadIdx.x] = 0.f;
  __syncthreads();
#pragma unroll
  for (int c = 0; c < CC; ++c) {
    float v = (i < KK1 && tv != 0.f) ? h2[i * PC + c] * tv : 0.f;
#pragma unroll
    for (int m = 32; m; m >>= 1) v += __shfl_xor(v, m, 64);
    if ((threadIdx.x & 63) == 0) atomicAdd(&sacc[c], v);
  }
  __syncthreads();
  if (threadIdx.x < CC) atomicAdd(&acc[threadIdx.x], sacc[threadIdx.x]);
}

__global__ void k_final(const float* __restrict__ acc, float* __restrict__ out) {
  if (threadIdx.x != 0 || blockIdx.x != 0) return;
  float v[CC];
  float m = -1e30f;
#pragma unroll
  for (int c = 0; c < CC; ++c) {
    v[c] = acc[c] / (float)KK2;
    if (v[c] > m) m = v[c];
  }
  float s = 0.f;
#pragma unroll
  for (int c = 0; c < CC; ++c) s += expf(v[c] - m);
  float l = logf(s);
#pragma unroll
  for (int c = 0; c < CC; ++c) out[c] = v[c] - m - l;
}

// ---------------- driver ----------------
extern "C" void kernel_launch(void* const* d_in, const int* in_sizes, int n_in,
                              void* d_out, int out_size, void* d_ws, size_t ws_size,
                              hipStream_t stream) {
  const float* x      = (const float*)d_in[0];
  const int*   esrc   = (const int*)d_in[1];
  const int*   edst   = (const int*)d_in[2];
  const float* W1     = (const float*)d_in[3];
  const float* b1     = (const float*)d_in[4];
  const float* w1root = (const float*)d_in[5];
  const float* w1rel  = (const float*)d_in[6];
  const float* p1b    = (const float*)d_in[7];
  const float* W2     = (const float*)d_in[8];
  const float* b2     = (const float*)d_in[9];
  const float* w2root = (const float*)d_in[10];
  const float* w2rel  = (const float*)d_in[11];
  const float* p2b    = (const float*)d_in[12];
  float* out = (float*)d_out;

  char* w = (char*)d_ws;
  size_t off = 0;
  auto alloc = [&](size_t bytes) -> char* {
    char* p = w + off;
    off += (bytes + 255) & ~(size_t)255;
    return p;
  };
  float*    h0      = (float*)alloc((size_t)NN * HH * 4);   // dead after k_conv1 -> carved below
  float*    hbuf    = (float*)alloc((size_t)NN * HH * 4);   // h (post-relu)
  float*    dinv1   = (float*)alloc((size_t)NN * 4);
  float*    hrel1   = (float*)alloc((size_t)NN * 4);
  float*    score1  = (float*)alloc((size_t)NN * 4);
  int*      nidx    = (int*)  alloc((size_t)NN * 4);
  int*      csr     = (int*)  alloc((size_t)EE * 4);
  unsigned* packed  = (unsigned*)alloc((size_t)EE * 4);
  int*      rowst   = (int*)  alloc((size_t)(NN + 1) * 4);
  unsigned* Hist    = (unsigned*)alloc((size_t)ABLK * NBIN * 4);   // 512 KB
  unsigned* Tot     = (unsigned*)alloc((size_t)NBIN * 4);
  unsigned* BOff    = (unsigned*)alloc((size_t)(NBIN + 1) * 4);
  // control region (one memset): ghist(8KB) + ctl1 + ctl2 + acc
  char*     ctlreg  = alloc(8192 + 256);
  unsigned* ghist   = (unsigned*)ctlreg;
  TopkCtl*  ctl1    = (TopkCtl*)(ctlreg + 8192);
  TopkCtl*  ctl2    = (TopkCtl*)(ctlreg + 8192 + 32);
  float*    acc     = (float*)(ctlreg + 8192 + 64);

  // stage-2 buffers carved out of h0's region (h0 dead after k_conv1)
  size_t off2 = 0;
  auto alloc2 = [&](size_t bytes) -> char* {
    char* p = (char*)h0 + off2;
    off2 += (bytes + 255) & ~(size_t)255;
    return p;
  };
  float* x1      = (float*)alloc2((size_t)KK1 * HH * 4);
  float* h20     = (float*)alloc2((size_t)KK1 * PC * 4 + 256);  // +pad for kq-overread
  float* h2      = (float*)alloc2((size_t)KK1 * PC * 4 + 256);
  float* dinv2   = (float*)alloc2((size_t)KK1 * 4);
  float* h2rel   = (float*)alloc2((size_t)KK1 * 4);
  float* score2  = (float*)alloc2((size_t)KK1 * 4);
  int*   orig_of = (int*)  alloc2((size_t)KK1 * 4);

  const int BN  = (NN + 255) / 256;   // 391
  const int BK1 = (KK1 + 255) / 256;  // 98

  // ---- control region zero (ghist, ctl1, ctl2, acc) ----
  hipMemsetAsync(ctlreg, 0, 8192 + 256, stream);

  // ---- conv1 GEMM ----
  k_xw1<<<NN / 16, 256, 0, stream>>>(x, W1, h0);

  // ---- CSR build: atomic-free bucket sort (also produces rowstart + dinv1) ----
  k_bhist<<<ABLK, 256, 0, stream>>>(edst, Hist);
  k_bcursor<<<NBIN / 64, 64, 0, stream>>>(Hist, Tot);
  k_bscan<<<1, NBIN, 0, stream>>>(Tot, BOff);
  k_bscatter<<<ABLK, 256, 0, stream>>>(esrc, edst, Hist, BOff, packed);
  k_bfine<<<NBUCK, 256, 0, stream>>>(packed, BOff, rowst, dinv1, csr);

  // ---- conv1 gather + relu + pool1 score init (fused) ----
  k_conv1<<<(NN + 3) / 4, 256, 0, stream>>>(h0, dinv1, rowst, csr, b1, w1root, w1rel,
                                            p1b, hbuf, score1, hrel1);
  k_scoreg<<<(NN + 15) / 16, 256, 0, stream>>>(rowst, csr, hrel1, score1);

  // ---- pool1 top-k: 3 fused radix passes ----
  k_topk_pass<0><<<BN, 256, 0, stream>>>(score1, NN, KK1, ctl1, ghist, BN);
  k_topk_pass<1><<<BN, 256, 0, stream>>>(score1, NN, KK1, ctl1, ghist, BN);
  k_topk_pass<2><<<BN, 256, 0, stream>>>(score1, NN, KK1, ctl1, ghist, BN);
  k_select1<<<BN, 256, 0, stream>>>(score1, hbuf, ctl1, nidx, orig_of, x1);

  // ---- conv2 via masked CSR sweeps (deg2 + xw2 fused) ----
  k_deg2xw2<<<DEG2_BLKS + XW2_BLKS, 256, 0, stream>>>(orig_of, rowst, csr, nidx,
                                                      dinv2, x1, W2, h20);
  k_conv2<<<(KK1 + 3) / 4, 256, 0, stream>>>(h20, dinv2, orig_of, rowst, csr, nidx,
                                             b2, w2root, w2rel, p2b, h2, score2, h2rel);
  k_score2g<<<(KK1 + 15) / 16, 256, 0, stream>>>(orig_of, rowst, csr, nidx, h2rel, score2);

  // ---- pool2 top-k: 3 fused radix passes + mean + log_softmax ----
  k_topk_pass<0><<<BK1, 256, 0, stream>>>(score2, KK1, KK2, ctl2, ghist, BK1);
  k_topk_pass<1><<<BK1, 256, 0, stream>>>(score2, KK1, KK2, ctl2, ghist, BK1);
  k_topk_pass<2><<<BK1, 256, 0, stream>>>(score2, KK1, KK2, ctl2, ghist, BK1);
  k_final_accum<<<BK1, 256, 0, stream>>>(score2, h2, ctl2, acc);
  k_final<<<1, 64, 0, stream>>>(acc, out);
}

// Round 9
// 429.199 us; speedup vs baseline: 1.2232x; 1.2232x over previous
//
#include <hip/hip_runtime.h>
#include <math.h>

#define NN 100000
#define EE 3200000
#define FF 128
#define HH 16
#define CC 10
#define PC 12           // padded conv2 feature stride (float4-friendly)
#define KK1 25000
#define KK2 6250

// bucket-sort CSR build parameters
#define NBIN 512        // coarse buckets; used = ceil(NN/256) = 391
#define BUCK_SHIFT 8    // bucket = dst >> 8  (256 nodes per bucket)
#define BUCK_MASK 255
#define ABLK 256        // blocks in passes A and C
#define EPB (EE / ABLK) // 12500 edges per block (exact)
#define NBUCK ((NN + 255) / 256)  // 391
#define XW1_BLKS (NN / 16)                 // 6250

#define DEG2_BLKS ((KK1 + 15) / 16)        // 1563
#define XW2_BLKS ((KK1 * PC + 255) / 256)  // 1172

struct SelState {
  unsigned prefix;
  unsigned kcur;
  unsigned ctr_gt;
  unsigned ctr_eq;
  unsigned hist[256];
};

__device__ __forceinline__ unsigned fkey(float f) {
  unsigned u = __float_as_uint(f);
  return (u & 0x80000000u) ? ~u : (u | 0x80000000u);
}

// ---------------- state init: st1, st2, acc in one tiny dispatch ----------------
__global__ __launch_bounds__(512) void k_state_combo(SelState* st1, SelState* st2,
                                                     float* acc) {
  int t = threadIdx.x;
  unsigned* a1 = (unsigned*)st1;
  unsigned* a2 = (unsigned*)st2;
  const int W = sizeof(SelState) / 4;   // 260
  if (t < W) a1[t] = 0u;
  if (t < W) a2[t] = 0u;
  if (t < CC) acc[t] = 0.f;
  if (t == 0) { st1->kcur = KK1; st2->kcur = KK2; }
}

// ---------------- fused conv1-GEMM + coarse edge histogram ----------------
__global__ __launch_bounds__(256) void k_xw1_bhist(const float* __restrict__ x,
                                                   const float* __restrict__ W1,
                                                   float* __restrict__ h0,
                                                   const int* __restrict__ dst,
                                                   unsigned* __restrict__ Hist) {
  __shared__ float smem[FF * HH + 16 * FF];   // 16 KB
  int b = blockIdx.x;
  int t = threadIdx.x;
  if (b < XW1_BLKS) {
    float* sW = smem;
    float* sx = smem + FF * HH;
    for (int i = t; i < FF * HH; i += 256) sW[i] = W1[i];
    int base = b * 16;
    for (int i = t; i < 16 * FF; i += 256) {
      int r = i >> 7, c = i & 127;
      sx[r * FF + c] = x[(size_t)(base + r) * FF + c];
    }
    __syncthreads();
    int r = t >> 4;   // node in tile
    int o = t & 15;   // output col
    float acc = 0.f;
#pragma unroll
    for (int k = 0; k < FF; ++k) acc += sx[r * FF + k] * sW[k * HH + o];
    h0[(base + r) * HH + o] = acc;
  } else {
    unsigned* sh = (unsigned*)smem;
    int blk = b - XW1_BLKS;
    for (int i = t; i < NBIN; i += 256) sh[i] = 0;
    __syncthreads();
    int base = blk * EPB;
    for (int i = base + t; i < base + EPB; i += 256)
      atomicAdd(&sh[dst[i] >> BUCK_SHIFT], 1u);
    __syncthreads();
    for (int i = t; i < NBIN; i += 256) Hist[blk * NBIN + i] = sh[i];
  }
}

// ---------------- fused per-bucket column prefix + bucket-offset scan ------------
__global__ __launch_bounds__(512) void k_bcursor_scan(unsigned* __restrict__ Hist,
                                                      unsigned* __restrict__ BucketOff) {
  __shared__ unsigned s[NBIN];
  int t = threadIdx.x;          // 0..511 == bin
  unsigned run = 0;
  for (int b = 0; b < ABLK; ++b) {
    unsigned c = Hist[b * NBIN + t];
    Hist[b * NBIN + t] = run;          // becomes per-block exclusive prefix
    run += c;
  }
  unsigned v = run;
  s[t] = v;
  __syncthreads();
  for (int off = 1; off < NBIN; off <<= 1) {
    unsigned u = (t >= off) ? s[t - off] : 0;
    __syncthreads();
    s[t] += u;
    __syncthreads();
  }
  BucketOff[t] = s[t] - v;
  if (t == NBIN - 1) BucketOff[NBIN] = s[t];   // == EE
}

// packed = (dst&255)<<17 | src   (src < 2^17)
__global__ __launch_bounds__(256) void k_bscatter(const int* __restrict__ src,
                                                  const int* __restrict__ dst,
                                                  const unsigned* __restrict__ Hist,
                                                  const unsigned* __restrict__ BucketOff,
                                                  unsigned* __restrict__ packed) {
  __shared__ unsigned cur[NBIN];
  int t = threadIdx.x;
  for (int i = t; i < NBIN; i += 256)
    cur[i] = BucketOff[i] + Hist[blockIdx.x * NBIN + i];
  __syncthreads();
  int base = blockIdx.x * EPB;
  for (int i = base + t; i < base + EPB; i += 256) {
    int d = dst[i];
    unsigned pos = atomicAdd(&cur[d >> BUCK_SHIFT], 1u);
    packed[pos] = ((unsigned)(d & BUCK_MASK) << 17) | (unsigned)src[i];
  }
}

__global__ __launch_bounds__(256) void k_bfine(const unsigned* __restrict__ packed,
                                               const unsigned* __restrict__ BucketOff,
                                               int* __restrict__ rowstart,
                                               float* __restrict__ dinv,
                                               int* __restrict__ csr) {
  __shared__ unsigned fcnt[256], fpos[256], fcur[256];
  int bin = blockIdx.x;
  int t = threadIdx.x;
  unsigned b0 = BucketOff[bin], b1 = BucketOff[bin + 1];
  fcnt[t] = 0;
  __syncthreads();
  for (unsigned e = b0 + t; e < b1; e += 256)
    atomicAdd(&fcnt[packed[e] >> 17], 1u);
  __syncthreads();
  unsigned v = fcnt[t];
  fpos[t] = v;
  __syncthreads();
  for (int off = 1; off < 256; off <<= 1) {
    unsigned u = (t >= off) ? fpos[t - off] : 0;
    __syncthreads();
    fpos[t] += u;
    __syncthreads();
  }
  unsigned excl = fpos[t] - v;
  fcur[t] = b0 + excl;
  int node = bin * 256 + t;
  if (node < NN) {
    rowstart[node] = (int)(b0 + excl);
    dinv[node] = rsqrtf((float)v + 1.0f);    // deg = cnt + 1 (self-loop)
  }
  if (bin == 0 && t == 0) rowstart[NN] = EE;
  __syncthreads();
  for (unsigned e = b0 + t; e < b1; e += 256) {
    unsigned p = packed[e];
    unsigned pos = atomicAdd(&fcur[p >> 17], 1u);
    csr[pos] = (int)(p & 0x1FFFFu);
  }
}

// ---------------- conv1: wave-per-node, 64 edges in flight (unroll x4) ----------
__global__ __launch_bounds__(256) void k_conv1(const float* __restrict__ h0,
                                               const float* __restrict__ dinv,
                                               const int* __restrict__ rowstart,
                                               const int* __restrict__ csr,
                                               const float* __restrict__ b1,
                                               const float* __restrict__ wroot,
                                               const float* __restrict__ wrel,
                                               const float* __restrict__ bp,
                                               float* __restrict__ h,
                                               float* __restrict__ score,
                                               float* __restrict__ hrel) {
  int node = blockIdx.x * 4 + (threadIdx.x >> 6);
  if (node >= NN) return;
  int lane = threadIdx.x & 63;
  int eslot = lane >> 2;          // 0..15
  int kq = lane & 3;              // float4 quarter
  int s0 = rowstart[node], s1 = rowstart[node + 1];
  float4 a0 = make_float4(0.f, 0.f, 0.f, 0.f);
  float4 a1 = a0, a2 = a0, a3 = a0;
  for (int base = s0; base < s1; base += 64) {
    int i0 = base + eslot;
    int i1 = base + 16 + eslot;
    int i2 = base + 32 + eslot;
    int i3 = base + 48 + eslot;
    bool o0 = i0 < s1, o1 = i1 < s1, o2 = i2 < s1, o3 = i3 < s1;
    int v0 = o0 ? csr[i0] : 0;
    int v1 = o1 ? csr[i1] : 0;
    int v2 = o2 ? csr[i2] : 0;
    int v3 = o3 ? csr[i3] : 0;
    float d0 = o0 ? dinv[v0] : 0.f;
    float d1 = o1 ? dinv[v1] : 0.f;
    float d2 = o2 ? dinv[v2] : 0.f;
    float d3 = o3 ? dinv[v3] : 0.f;
    float4 h0v = *(const float4*)(h0 + v0 * HH + kq * 4);
    float4 h1v = *(const float4*)(h0 + v1 * HH + kq * 4);
    float4 h2v = *(const float4*)(h0 + v2 * HH + kq * 4);
    float4 h3v = *(const float4*)(h0 + v3 * HH + kq * 4);
    a0.x += h0v.x * d0; a0.y += h0v.y * d0; a0.z += h0v.z * d0; a0.w += h0v.w * d0;
    a1.x += h1v.x * d1; a1.y += h1v.y * d1; a1.z += h1v.z * d1; a1.w += h1v.w * d1;
    a2.x += h2v.x * d2; a2.y += h2v.y * d2; a2.z += h2v.z * d2; a2.w += h2v.w * d2;
    a3.x += h3v.x * d3; a3.y += h3v.y * d3; a3.z += h3v.z * d3; a3.w += h3v.w * d3;
  }
  float ax = (a0.x + a1.x) + (a2.x + a3.x);
  float ay = (a0.y + a1.y) + (a2.y + a3.y);
  float az = (a0.z + a1.z) + (a2.z + a3.z);
  float aw = (a0.w + a1.w) + (a2.w + a3.w);
#pragma unroll
  for (int m = 4; m <= 32; m <<= 1) {
    ax += __shfl_xor(ax, m);
    ay += __shfl_xor(ay, m);
    az += __shfl_xor(az, m);
    aw += __shfl_xor(aw, m);
  }
  float di = dinv[node];
  float4 hs = *(const float4*)(h0 + node * HH + kq * 4);
  float vx = ax * di + hs.x * di * di + b1[kq * 4 + 0];
  float vy = ay * di + hs.y * di * di + b1[kq * 4 + 1];
  float vz = az * di + hs.z * di * di + b1[kq * 4 + 2];
  float vw = aw * di + hs.w * di * di + b1[kq * 4 + 3];
  vx = vx > 0.f ? vx : 0.f;
  vy = vy > 0.f ? vy : 0.f;
  vz = vz > 0.f ? vz : 0.f;
  vw = vw > 0.f ? vw : 0.f;
  if (eslot == 0) {
    float4 o4 = make_float4(vx, vy, vz, vw);
    *(float4*)(h + node * HH + kq * 4) = o4;
  }
  float sr = vx * wroot[kq * 4] + vy * wroot[kq * 4 + 1] +
             vz * wroot[kq * 4 + 2] + vw * wroot[kq * 4 + 3];
  float sl = vx * wrel[kq * 4] + vy * wrel[kq * 4 + 1] +
             vz * wrel[kq * 4 + 2] + vw * wrel[kq * 4 + 3];
  sr += __shfl_xor(sr, 1);
  sr += __shfl_xor(sr, 2);
  sl += __shfl_xor(sl, 1);
  sl += __shfl_xor(sl, 2);
  if (lane == 0) {
    score[node] = sr + bp[0];
    hrel[node] = sl;
  }
}

// score[d] += sum over in-edges of hrel[src]; 16 lanes per node, no atomics
__global__ __launch_bounds__(256) void k_scoreg(const int* __restrict__ rowstart,
                                                const int* __restrict__ csr,
                                                const float* __restrict__ hrel,
                                                float* __restrict__ score) {
  int node = blockIdx.x * 16 + (threadIdx.x >> 4);
  if (node >= NN) return;
  int lane = threadIdx.x & 15;
  int s0 = rowstart[node], s1 = rowstart[node + 1];
  float sum = 0.f;
  for (int e = s0 + lane; e < s1; e += 16) sum += hrel[csr[e]];
#pragma unroll
  for (int m = 8; m; m >>= 1) sum += __shfl_xor(sum, m, 16);
  if (lane == 0) score[node] += sum;
}

// ---------------- radix top-k select (proven round-7 chain) ----------------
__global__ __launch_bounds__(256) void k_hist(const float* __restrict__ vals, int n,
                                              SelState* st, int pass) {
  __shared__ unsigned sh[256];
  int t = threadIdx.x;
  sh[t] = 0;
  __syncthreads();
  int i = blockIdx.x * 256 + t;
  if (i < n) {
    unsigned key = fkey(vals[i]);
    bool ok = true;
    if (pass != 0) ok = (key >> (32 - 8 * pass)) == st->prefix;
    if (ok) atomicAdd(&sh[(key >> (24 - 8 * pass)) & 255], 1u);
  }
  __syncthreads();
  if (sh[t]) atomicAdd(&st->hist[t], sh[t]);
}

// parallel: suffix-sum over 256 bins, unique winner updates prefix/kcur
__global__ __launch_bounds__(256) void k_scan(SelState* st) {
  __shared__ unsigned s[256];
  int t = threadIdx.x;
  unsigned kcur = st->kcur;      // read BEFORE any update
  unsigned v = st->hist[t];
  s[t] = v;
  __syncthreads();
  for (int off = 1; off < 256; off <<= 1) {
    unsigned u = (t + off < 256) ? s[t + off] : 0;
    __syncthreads();
    s[t] += u;
    __syncthreads();
  }
  unsigned Sme = s[t];
  unsigned Snext = (t < 255) ? s[t + 1] : 0;
  if (Sme >= kcur && Snext < kcur) {
    st->prefix = (st->prefix << 8) | (unsigned)t;
    st->kcur = kcur - Snext;
  }
  st->hist[t] = 0;
}

// pool1 selection with block-aggregated counters (2 returning atomics per block)
__global__ __launch_bounds__(256) void k_select1(const float* __restrict__ score,
                                                 const float* __restrict__ h,
                                                 SelState* st, int* __restrict__ new_idx,
                                                 int* __restrict__ orig_of,
                                                 float* __restrict__ x1) {
  int i = blockIdx.x * 256 + threadIdx.x;
  int lane = threadIdx.x & 63;
  int wid = threadIdx.x >> 6;
  float sc = 0.f;
  bool gt = false, eq = false;
  unsigned T = st->prefix;
  if (i < NN) {
    sc = score[i];
    unsigned key = fkey(sc);
    gt = key > T;
    eq = key == T;
  }
  unsigned long long mgt = __ballot(gt);
  unsigned long long meq = __ballot(eq);
  __shared__ int wgt[4], weq[4];
  if (lane == 0) {
    wgt[wid] = __popcll(mgt);
    weq[wid] = __popcll(meq);
  }
  __syncthreads();
  if (threadIdx.x == 0) {
    int tg = wgt[0] + wgt[1] + wgt[2] + wgt[3];
    int te = weq[0] + weq[1] + weq[2] + weq[3];
    int bg = tg ? (int)atomicAdd(&st->ctr_gt, (unsigned)tg) : 0;
    int be = te ? (int)atomicAdd(&st->ctr_eq, (unsigned)te) : 0;
    int r = bg;
    for (int w2 = 0; w2 < 4; ++w2) { int c = wgt[w2]; wgt[w2] = r; r += c; }
    r = be;
    for (int w2 = 0; w2 < 4; ++w2) { int c = weq[w2]; weq[w2] = r; r += c; }
  }
  __syncthreads();
  if (i >= NN) return;
  unsigned long long ltmask = (1ull << lane) - 1ull;
  int id = -1;
  if (gt) {
    id = wgt[wid] + (int)__popcll(mgt & ltmask);
  } else if (eq) {
    unsigned p = (unsigned)(weq[wid] + (int)__popcll(meq & ltmask));
    unsigned kneed = st->kcur;
    if (p < kneed) id = (KK1 - (int)kneed) + (int)p;
  }
  new_idx[i] = id;
  if (id >= 0) {
    orig_of[id] = i;
    float tv = tanhf(sc);
#pragma unroll
    for (int k = 0; k < HH; ++k) x1[id * HH + k] = h[i * HH + k] * tv;
  }
}

// ---------------- fused deg2 + xw2 (independent work, one dispatch) --------------
__global__ __launch_bounds__(256) void k_deg2xw2(const int* __restrict__ orig_of,
                                                 const int* __restrict__ rowstart,
                                                 const int* __restrict__ csr,
                                                 const int* __restrict__ nidx,
                                                 float* __restrict__ dinv2,
                                                 const float* __restrict__ x1,
                                                 const float* __restrict__ W2,
                                                 float* __restrict__ h20) {
  int b = blockIdx.x;
  if (b < DEG2_BLKS) {
    int j = b * 16 + (threadIdx.x >> 4);
    if (j >= KK1) return;
    int lane = threadIdx.x & 15;
    int o = orig_of[j];
    int s0 = rowstart[o], s1 = rowstart[o + 1];
    int c = 0;
    for (int e = s0 + lane; e < s1; e += 16) c += (nidx[csr[e]] >= 0) ? 1 : 0;
#pragma unroll
    for (int m = 8; m; m >>= 1) c += __shfl_xor(c, m, 16);
    if (lane == 0) dinv2[j] = rsqrtf((float)c + 1.0f);
  } else {
    int t = (b - DEG2_BLKS) * 256 + threadIdx.x;
    if (t >= KK1 * PC) return;
    int node = t / PC;
    int o = t - node * PC;
    float acc = 0.f;
    if (o < CC) {
#pragma unroll
      for (int k = 0; k < HH; ++k) acc += x1[node * HH + k] * W2[k * CC + o];
    }
    h20[t] = acc;
  }
}

// conv2: wave-per-node, edge-parallel float4 (stride-12 rows; kq=3 lanes inert)
__global__ __launch_bounds__(256) void k_conv2(const float* __restrict__ h20,
                                               const float* __restrict__ dinv2,
                                               const int* __restrict__ orig_of,
                                               const int* __restrict__ rowstart,
                                               const int* __restrict__ csr,
                                               const int* __restrict__ nidx,
                                               const float* __restrict__ b2,
                                               const float* __restrict__ wroot,
                                               const float* __restrict__ wrel,
                                               const float* __restrict__ bp,
                                               float* __restrict__ h2,
                                               float* __restrict__ score2,
                                               float* __restrict__ h2rel) {
  int j = blockIdx.x * 4 + (threadIdx.x >> 6);
  if (j >= KK1) return;
  int lane = threadIdx.x & 63;
  int eslot = lane >> 2;
  int kq = lane & 3;
  int o = orig_of[j];
  int s0 = rowstart[o], s1 = rowstart[o + 1];
  float ax = 0.f, ay = 0.f, az = 0.f, aw = 0.f;
  for (int base = s0; base < s1; base += 16) {
    int idx = base + eslot;
    bool on = idx < s1;
    int sv = on ? nidx[csr[idx]] : -1;
    float dv = (sv >= 0) ? dinv2[sv] : 0.f;
    int sva = (sv >= 0) ? sv : 0;
    float4 hv = *(const float4*)(h20 + sva * PC + ((kq < 3) ? kq * 4 : 8));
    if (kq == 3) dv = 0.f;
    ax += hv.x * dv;
    ay += hv.y * dv;
    az += hv.z * dv;
    aw += hv.w * dv;
  }
#pragma unroll
  for (int m = 4; m <= 32; m <<= 1) {
    ax += __shfl_xor(ax, m);
    ay += __shfl_xor(ay, m);
    az += __shfl_xor(az, m);
    aw += __shfl_xor(aw, m);
  }
  float di = dinv2[j];
  int kb = (kq < 3) ? kq * 4 : 8;
  float4 hs = *(const float4*)(h20 + j * PC + kb);
  float bx = (kb + 0 < CC) ? b2[kb + 0] : 0.f;
  float by = (kb + 1 < CC) ? b2[kb + 1] : 0.f;
  float bz = (kb + 2 < CC) ? b2[kb + 2] : 0.f;
  float bw = (kb + 3 < CC) ? b2[kb + 3] : 0.f;
  float vx = ax * di + hs.x * di * di + bx;
  float vy = ay * di + hs.y * di * di + by;
  float vz = az * di + hs.z * di * di + bz;
  float vw = aw * di + hs.w * di * di + bw;
  if (kq == 3) { vx = vy = vz = vw = 0.f; }
  if (kb + 2 >= CC) vz = 0.f;
  if (kb + 3 >= CC) vw = 0.f;
  if (eslot == 0 && kq < 3) {
    float4 o4 = make_float4(vx, vy, vz, vw);
    *(float4*)(h2 + j * PC + kq * 4) = o4;
  }
  float wrx = (kb + 0 < CC) ? wroot[kb + 0] : 0.f;
  float wry = (kb + 1 < CC) ? wroot[kb + 1] : 0.f;
  float wrz = (kb + 2 < CC) ? wroot[kb + 2] : 0.f;
  float wrw = (kb + 3 < CC) ? wroot[kb + 3] : 0.f;
  float wlx = (kb + 0 < CC) ? wrel[kb + 0] : 0.f;
  float wly = (kb + 1 < CC) ? wrel[kb + 1] : 0.f;
  float wlz = (kb + 2 < CC) ? wrel[kb + 2] : 0.f;
  float wlw = (kb + 3 < CC) ? wrel[kb + 3] : 0.f;
  float sr = (kq == 3) ? 0.f : (vx * wrx + vy * wry + vz * wrz + vw * wrw);
  float sl = (kq == 3) ? 0.f : (vx * wlx + vy * wly + vz * wlz + vw * wlw);
  sr += __shfl_xor(sr, 1);
  sr += __shfl_xor(sr, 2);
  sl += __shfl_xor(sl, 1);
  sl += __shfl_xor(sl, 2);
  if (lane == 0) {
    score2[j] = sr + bp[0];
    h2rel[j] = sl;
  }
}

// score2[j] += sum over surviving in-edges of h2rel[src]; 16 lanes per node
__global__ __launch_bounds__(256) void k_score2g(const int* __restrict__ orig_of,
                                                 const int* __restrict__ rowstart,
                                                 const int* __restrict__ csr,
                                                 const int* __restrict__ nidx,
                                                 const float* __restrict__ h2rel,
                                                 float* __restrict__ score2) {
  int j = blockIdx.x * 16 + (threadIdx.x >> 4);
  if (j >= KK1) return;
  int lane = threadIdx.x & 15;
  int o = orig_of[j];
  int s0 = rowstart[o], s1 = rowstart[o + 1];
  float sum = 0.f;
  for (int e = s0 + lane; e < s1; e += 16) {
    int s = nidx[csr[e]];
    if (s >= 0) sum += h2rel[s];
  }
#pragma unroll
  for (int m = 8; m; m >>= 1) sum += __shfl_xor(sum, m, 16);
  if (lane == 0) score2[j] += sum;
}

// pool2 selection folded into output accumulator; wave+LDS reduce, 10 atomics/block
__global__ __launch_bounds__(256) void k_final_accum(const float* __restrict__ score,
                                                     const float* __restrict__ h2,
                                                     SelState* st, float* __restrict__ acc) {
  int i = blockIdx.x * blockDim.x + threadIdx.x;
  float tv = 0.f;
  if (i < KK1) {
    float sc = score[i];
    unsigned key = fkey(sc);
    unsigned T = st->prefix;
    bool keep = false;
    if (key > T) {
      keep = true;
    } else if (key == T) {
      unsigned p = atomicAdd(&st->ctr_eq, 1u);
      keep = (p < st->kcur);
    }
    if (keep) tv = tanhf(sc);
  }
  __shared__ float sacc[CC];
  if (threadIdx.x < CC) sacc[threadIdx.x] = 0.f;
  __syncthreads();
#pragma unroll
  for (int c = 0; c < CC; ++c) {
    float v = (i < KK1 && tv != 0.f) ? h2[i * PC + c] * tv : 0.f;
#pragma unroll
    for (int m = 32; m; m >>= 1) v += __shfl_xor(v, m, 64);
    if ((threadIdx.x & 63) == 0) atomicAdd(&sacc[c], v);
  }
  __syncthreads();
  if (threadIdx.x < CC) atomicAdd(&acc[threadIdx.x], sacc[threadIdx.x]);
}

__global__ void k_final(const float* __restrict__ acc, float* __restrict__ out) {
  if (threadIdx.x != 0 || blockIdx.x != 0) return;
  float v[CC];
  float m = -1e30f;
#pragma unroll
  for (int c = 0; c < CC; ++c) {
    v[c] = acc[c] / (float)KK2;
    if (v[c] > m) m = v[c];
  }
  float s = 0.f;
#pragma unroll
  for (int c = 0; c < CC; ++c) s += expf(v[c] - m);
  float l = logf(s);
#pragma unroll
  for (int c = 0; c < CC; ++c) out[c] = v[c] - m - l;
}

// ---------------- driver ----------------
extern "C" void kernel_launch(void* const* d_in, const int* in_sizes, int n_in,
                              void* d_out, int out_size, void* d_ws, size_t ws_size,
                              hipStream_t stream) {
  const float* x      = (const float*)d_in[0];
  const int*   esrc   = (const int*)d_in[1];
  const int*   edst   = (const int*)d_in[2];
  const float* W1     = (const float*)d_in[3];
  const float* b1     = (const float*)d_in[4];
  const float* w1root = (const float*)d_in[5];
  const float* w1rel  = (const float*)d_in[6];
  const float* p1b    = (const float*)d_in[7];
  const float* W2     = (const float*)d_in[8];
  const float* b2     = (const float*)d_in[9];
  const float* w2root = (const float*)d_in[10];
  const float* w2rel  = (const float*)d_in[11];
  const float* p2b    = (const float*)d_in[12];
  float* out = (float*)d_out;

  char* w = (char*)d_ws;
  size_t off = 0;
  auto alloc = [&](size_t bytes) -> char* {
    char* p = w + off;
    off += (bytes + 255) & ~(size_t)255;
    return p;
  };
  float*    h0      = (float*)alloc((size_t)NN * HH * 4);   // dead after k_conv1 -> carved below
  float*    hbuf    = (float*)alloc((size_t)NN * HH * 4);   // h (post-relu)
  float*    dinv1   = (float*)alloc((size_t)NN * 4);
  float*    hrel1   = (float*)alloc((size_t)NN * 4);
  float*    score1  = (float*)alloc((size_t)NN * 4);
  int*      nidx    = (int*)  alloc((size_t)NN * 4);
  int*      csr     = (int*)  alloc((size_t)EE * 4);
  unsigned* packed  = (unsigned*)alloc((size_t)EE * 4);
  int*      rowst   = (int*)  alloc((size_t)(NN + 1) * 4);
  unsigned* Hist    = (unsigned*)alloc((size_t)ABLK * NBIN * 4);   // 512 KB
  unsigned* BOff    = (unsigned*)alloc((size_t)(NBIN + 1) * 4);
  SelState* st1     = (SelState*)alloc(sizeof(SelState));
  SelState* st2     = (SelState*)alloc(sizeof(SelState));
  float*    acc     = (float*)alloc(256);

  // stage-2 buffers carved out of h0's region (h0 dead after k_conv1)
  size_t off2 = 0;
  auto alloc2 = [&](size_t bytes) -> char* {
    char* p = (char*)h0 + off2;
    off2 += (bytes + 255) & ~(size_t)255;
    return p;
  };
  float* x1      = (float*)alloc2((size_t)KK1 * HH * 4);
  float* h20     = (float*)alloc2((size_t)KK1 * PC * 4 + 256);  // +pad for kq-overread
  float* h2      = (float*)alloc2((size_t)KK1 * PC * 4 + 256);
  float* dinv2   = (float*)alloc2((size_t)KK1 * 4);
  float* h2rel   = (float*)alloc2((size_t)KK1 * 4);
  float* score2  = (float*)alloc2((size_t)KK1 * 4);
  int*   orig_of = (int*)  alloc2((size_t)KK1 * 4);

  const int BN  = (NN + 255) / 256;   // 391
  const int BK1 = (KK1 + 255) / 256;  // 98

  // ---- state init (st1, st2, acc) ----
  k_state_combo<<<1, 512, 0, stream>>>(st1, st2, acc);

  // ---- conv1 GEMM + coarse edge hist (fused, independent) ----
  k_xw1_bhist<<<XW1_BLKS + ABLK, 256, 0, stream>>>(x, W1, h0, edst, Hist);

  // ---- CSR build ----
  k_bcursor_scan<<<1, 512, 0, stream>>>(Hist, BOff);
  k_bscatter<<<ABLK, 256, 0, stream>>>(esrc, edst, Hist, BOff, packed);
  k_bfine<<<NBUCK, 256, 0, stream>>>(packed, BOff, rowst, dinv1, csr);

  // ---- conv1 gather + relu + pool1 score init (fused) ----
  k_conv1<<<(NN + 3) / 4, 256, 0, stream>>>(h0, dinv1, rowst, csr, b1, w1root, w1rel,
                                            p1b, hbuf, score1, hrel1);
  k_scoreg<<<(NN + 15) / 16, 256, 0, stream>>>(rowst, csr, hrel1, score1);

  // ---- pool1 top-k (radix select) ----
  for (int p = 0; p < 4; ++p) {
    k_hist<<<BN, 256, 0, stream>>>(score1, NN, st1, p);
    k_scan<<<1, 256, 0, stream>>>(st1);
  }
  k_select1<<<BN, 256, 0, stream>>>(score1, hbuf, st1, nidx, orig_of, x1);

  // ---- conv2 via masked CSR sweeps (deg2 + xw2 fused) ----
  k_deg2xw2<<<DEG2_BLKS + XW2_BLKS, 256, 0, stream>>>(orig_of, rowst, csr, nidx,
                                                      dinv2, x1, W2, h20);
  k_conv2<<<(KK1 + 3) / 4, 256, 0, stream>>>(h20, dinv2, orig_of, rowst, csr, nidx,
                                             b2, w2root, w2rel, p2b, h2, score2, h2rel);
  k_score2g<<<(KK1 + 15) / 16, 256, 0, stream>>>(orig_of, rowst, csr, nidx, h2rel, score2);

  // ---- pool2 top-k + mean + log_softmax ----
  for (int p = 0; p < 4; ++p) {
    k_hist<<<BK1, 256, 0, stream>>>(score2, KK1, st2, p);
    k_scan<<<1, 256, 0, stream>>>(st2);
  }
  k_final_accum<<<BK1, 256, 0, stream>>>(score2, h2, st2, acc);
  k_final<<<1, 64, 0, stream>>>(acc, out);
}